// Round 3
// baseline (244.833 us; speedup 1.0000x reference)
//
#include <hip/hip_runtime.h>
#include <hip/hip_bf16.h>

#define B_ 64
#define A_ 8732
#define G_ 50
#define C_ 21

// ---------------- Kernel 1: match + box loss + CE ----------------
__global__ __launch_bounds__(256) void k_match_ce(
    const float* __restrict__ preg,   // [B,4,A] fp32
    const float* __restrict__ pcls,   // [B,C,A] fp32
    const float* __restrict__ ancs,   // [A,4] cx,cy,w,h fp32
    const float* __restrict__ gbox,   // [B,G,4] ltrb fp32
    const int*   __restrict__ glab,   // [B,G] int32
    float* __restrict__ loss_neg,     // [B*A]
    int*   __restrict__ pos_cnt,      // [B]
    float* __restrict__ ce_pos_sum,   // [B]
    float* __restrict__ sl1_sum)      // [1]
{
    __shared__ float sg[G_][4];
    __shared__ int   slb[G_];
    const int b = blockIdx.y;
    const int a = blockIdx.x * 256 + threadIdx.x;

    for (int i = threadIdx.x; i < G_; i += 256) {
        const float4 gp = *(const float4*)(gbox + ((size_t)b * G_ + i) * 4);
        sg[i][0] = gp.x; sg[i][1] = gp.y; sg[i][2] = gp.z; sg[i][3] = gp.w;
        slb[i]   = glab[b * G_ + i];
    }
    __syncthreads();
    if (a >= A_) return;

    // anchor xywh -> ltrb
    const float4 ap = *(const float4*)(ancs + (size_t)a * 4);
    const float acx = ap.x, acy = ap.y, aw = ap.z, ah = ap.w;
    const float al = acx - aw * 0.5f, at = acy - ah * 0.5f;
    const float ar = acx + aw * 0.5f, ab = acy + ah * 0.5f;
    const float area_a = (ar - al) * (ab - at);

    // argmax IoU over GTs (first-max wins, masked gts get -1)
    float best = -1.0f; int bi = 0;
    for (int g = 0; g < G_; ++g) {
        const float gl = sg[g][0], gt = sg[g][1], gr = sg[g][2], gb = sg[g][3];
        float ix = fminf(gr, ar) - fmaxf(gl, al);
        float iy = fminf(gb, ab) - fmaxf(gt, at);
        ix = fmaxf(ix, 0.0f); iy = fmaxf(iy, 0.0f);
        const float inter  = ix * iy;
        const float area_g = (gr - gl) * (gb - gt);
        const float uni    = fmaxf(area_g + area_a - inter, 1e-8f);
        const float iou    = (slb[g] > 0) ? inter / uni : -1.0f;
        if (iou > best) { best = iou; bi = g; }
    }
    const bool pos = (best >= 0.5f);
    const int  lab = pos ? slb[bi] : 0;

    // 21-class log-softmax CE at column a (dynamic index avoided via select)
    const float* pc = pcls + (size_t)b * C_ * A_ + a;
    float x[C_];
    float m = -1e30f, xl = 0.0f;
    #pragma unroll
    for (int c = 0; c < C_; ++c) {
        x[c] = pc[(size_t)c * A_];
        m = fmaxf(m, x[c]);
        xl = (c == lab) ? x[c] : xl;
    }
    float s = 0.0f;
    #pragma unroll
    for (int c = 0; c < C_; ++c) s += expf(x[c] - m);
    const float ce = m + logf(s) - xl;

    loss_neg[(size_t)b * A_ + a] = pos ? 0.0f : ce;

    if (pos) {
        const float gl = sg[bi][0], gt = sg[bi][1], gr = sg[bi][2], gb = sg[bi][3];
        const float gcx = (gl + gr) * 0.5f, gcy = (gt + gb) * 0.5f;
        const float gw = gr - gl, gh = gb - gt;
        float t[4];
        t[0] = (gcx - acx) / (aw * 0.1f);
        t[1] = (gcy - acy) / (ah * 0.1f);
        t[2] = logf(fmaxf(gw, 1e-6f) / aw) / 0.2f;
        t[3] = logf(fmaxf(gh, 1e-6f) / ah) / 0.2f;
        const float* pr = preg + (size_t)b * 4 * A_ + a;
        float sl1 = 0.0f;
        #pragma unroll
        for (int k = 0; k < 4; ++k) {
            const float d  = pr[(size_t)k * A_] - t[k];
            const float ad = fabsf(d);
            sl1 += (ad < 1.0f) ? 0.5f * d * d : ad - 0.5f;
        }
        atomicAdd(&pos_cnt[b], 1);
        atomicAdd(&ce_pos_sum[b], ce);
        atomicAdd(sl1_sum, sl1);
    }
}

// ---------------- Kernel 2: per-image OHEM top-K sum ----------------
__global__ __launch_bounds__(256) void k_ohem(
    const float* __restrict__ loss_neg,
    const int*   __restrict__ pos_cnt,
    const float* __restrict__ ce_pos_sum,
    float* __restrict__ acc_conf)
{
    __shared__ unsigned sv[A_];     // ~35 KB
    __shared__ int   swi[4];
    __shared__ float swf[4];
    const int b    = blockIdx.x;
    const int tid  = threadIdx.x;
    const int np   = pos_cnt[b];
    const int wid  = tid >> 6;
    const int lane = tid & 63;

    for (int i = tid; i < A_; i += 256)
        sv[i] = __float_as_uint(loss_neg[(size_t)b * A_ + i]);
    __syncthreads();

    if (np == 0) {
        // nums_pos clipped to EPS16; rank < 3*EPS16 selects only rank 0:
        // contribution = max_ce / EPS16 (l_pos term is 0).
        unsigned mx = 0u;
        for (int i = tid; i < A_; i += 256) mx = max(mx, sv[i]);
        for (int o = 32; o > 0; o >>= 1)
            mx = max(mx, (unsigned)__shfl_down((int)mx, o));
        if (lane == 0) swi[wid] = (int)mx;
        __syncthreads();
        if (tid == 0) {
            unsigned m2 = max(max((unsigned)swi[0], (unsigned)swi[1]),
                              max((unsigned)swi[2], (unsigned)swi[3]));
            const float l_neg = __uint_as_float(m2) * 1024.0f;  // 1/EPS16
            atomicAdd(acc_conf, l_neg * (1.0f / (float)B_));
        }
        return;
    }

    const int K = 3 * np;

    // greedy bit-descent: thr = K-th largest value (CE >= 0 => uint order == float order)
    unsigned thr = 0u;
    for (int bit = 31; bit >= 0; --bit) {
        const unsigned cand = thr | (1u << bit);
        int cnt = 0;
        for (int i = tid; i < A_; i += 256) cnt += (sv[i] >= cand) ? 1 : 0;
        for (int o = 32; o > 0; o >>= 1) cnt += __shfl_down(cnt, o);
        if (lane == 0) swi[wid] = cnt;
        __syncthreads();
        cnt = swi[0] + swi[1] + swi[2] + swi[3];
        __syncthreads();
        if (cnt >= K) thr = cand;
    }
    const float t = __uint_as_float(thr);

    // sum strictly above threshold + tie fill-in (value-exact under ties)
    float ssum = 0.0f; int cgt = 0;
    for (int i = tid; i < A_; i += 256) {
        const unsigned u = sv[i];
        if (u > thr) { ssum += __uint_as_float(u); ++cgt; }
    }
    for (int o = 32; o > 0; o >>= 1) {
        ssum += __shfl_down(ssum, o);
        cgt  += __shfl_down(cgt, o);
    }
    if (lane == 0) { swi[wid] = cgt; swf[wid] = ssum; }
    __syncthreads();
    if (tid == 0) {
        const int   ngt = swi[0] + swi[1] + swi[2] + swi[3];
        const float sgt = swf[0] + swf[1] + swf[2] + swf[3];
        const float fnp = (float)np;
        const float l_neg = (sgt + (float)(K - ngt) * t) / fnp;
        const float l_pos = ce_pos_sum[b] / fnp;
        atomicAdd(acc_conf, (l_neg + l_pos) * (1.0f / (float)B_));
    }
}

// ---------------- Kernel 3: finalize (fp32 out) ----------------
__global__ void k_final(const float* __restrict__ sl1_sum,
                        const int*   __restrict__ pos_cnt,
                        const float* __restrict__ acc_conf,
                        float* __restrict__ out)
{
    if (threadIdx.x == 0 && blockIdx.x == 0) {
        int tot = 0;
        for (int b = 0; b < B_; ++b) tot += pos_cnt[b];
        const float np_total = fmaxf((float)tot, 1.0f);
        const float l_box = sl1_sum[0] / np_total;
        out[0] = l_box + acc_conf[0];
    }
}

extern "C" void kernel_launch(void* const* d_in, const int* in_sizes, int n_in,
                              void* d_out, int out_size, void* d_ws, size_t ws_size,
                              hipStream_t stream)
{
    const float* preg = (const float*)d_in[0];
    const float* pcls = (const float*)d_in[1];
    const float* ancs = (const float*)d_in[2];
    const float* gbox = (const float*)d_in[3];
    const int*   glab = (const int*)d_in[4];
    float* out = (float*)d_out;   // reference output dtype is float32

    // workspace layout
    float* loss_neg   = (float*)d_ws;                        // B*A floats
    int*   pos_cnt    = (int*)(loss_neg + (size_t)B_ * A_);  // B ints
    float* ce_pos_sum = (float*)(pos_cnt + B_);              // B floats
    float* sl1_sum    = ce_pos_sum + B_;                     // 1 float
    float* acc_conf   = sl1_sum + 1;                         // 1 float

    // zero accumulators (ws is poisoned 0xAA before every call)
    hipMemsetAsync(pos_cnt, 0, (size_t)(B_ + B_ + 2) * sizeof(float), stream);

    dim3 g1((A_ + 255) / 256, B_);
    k_match_ce<<<g1, 256, 0, stream>>>(preg, pcls, ancs, gbox, glab,
                                       loss_neg, pos_cnt, ce_pos_sum, sl1_sum);
    k_ohem<<<B_, 256, 0, stream>>>(loss_neg, pos_cnt, ce_pos_sum, acc_conf);
    k_final<<<1, 64, 0, stream>>>(sl1_sum, pos_cnt, acc_conf, out);
}

// Round 4
// 134.512 us; speedup vs baseline: 1.8202x; 1.8202x over previous
//
#include <hip/hip_runtime.h>
#include <hip/hip_bf16.h>

#define B_ 64
#define A_ 8732
#define G_ 50
#define C_ 21

// ---------------- Kernel 1: match + box loss + CE ----------------
// Block-level reduction before atomics: 3 atomics/block instead of 3/positive-thread.
__global__ __launch_bounds__(256) void k_match_ce(
    const float* __restrict__ preg,   // [B,4,A]
    const float* __restrict__ pcls,   // [B,C,A]
    const float* __restrict__ ancs,   // [A,4] cx,cy,w,h
    const float* __restrict__ gbox,   // [B,G,4] ltrb
    const int*   __restrict__ glab,   // [B,G]
    float* __restrict__ loss_neg,     // [B*A]
    int*   __restrict__ pos_cnt,      // [B]
    float* __restrict__ ce_pos_sum,   // [B]
    float* __restrict__ sl1_b)        // [B]
{
    __shared__ float sg[G_][4];
    __shared__ int   slb[G_];
    __shared__ float redf[8];
    __shared__ int   redi[4];
    const int b    = blockIdx.y;
    const int tid  = threadIdx.x;
    const int wid  = tid >> 6;
    const int lane = tid & 63;
    const int a_r  = blockIdx.x * 256 + tid;
    const bool valid = a_r < A_;
    const int a = valid ? a_r : (A_ - 1);   // clamp: keeps all loads in-bounds

    for (int i = tid; i < G_; i += 256) {
        const float4 gp = *(const float4*)(gbox + ((size_t)b * G_ + i) * 4);
        sg[i][0] = gp.x; sg[i][1] = gp.y; sg[i][2] = gp.z; sg[i][3] = gp.w;
        slb[i]   = glab[b * G_ + i];
    }
    __syncthreads();

    // anchor xywh -> ltrb
    const float4 ap = *(const float4*)(ancs + (size_t)a * 4);
    const float acx = ap.x, acy = ap.y, aw = ap.z, ah = ap.w;
    const float al = acx - aw * 0.5f, at = acy - ah * 0.5f;
    const float ar = acx + aw * 0.5f, ab = acy + ah * 0.5f;
    const float area_a = (ar - al) * (ab - at);

    // argmax IoU over GTs (first-max wins, masked gts get -1); fast rcp division
    float best = -1.0f; int bi = 0;
    for (int g = 0; g < G_; ++g) {
        const float gl = sg[g][0], gt = sg[g][1], gr = sg[g][2], gb = sg[g][3];
        float ix = fminf(gr, ar) - fmaxf(gl, al);
        float iy = fminf(gb, ab) - fmaxf(gt, at);
        ix = fmaxf(ix, 0.0f); iy = fmaxf(iy, 0.0f);
        const float inter  = ix * iy;
        const float area_g = (gr - gl) * (gb - gt);
        const float uni    = fmaxf(area_g + area_a - inter, 1e-8f);
        const float iou    = (slb[g] > 0) ? inter * __builtin_amdgcn_rcpf(uni) : -1.0f;
        if (iou > best) { best = iou; bi = g; }
    }
    const bool pos = valid && (best >= 0.5f);
    const int  lab = pos ? slb[bi] : 0;

    // 21-class log-softmax CE at column a (dynamic index avoided via select)
    const float* pc = pcls + (size_t)b * C_ * A_ + a;
    float x[C_];
    float m = -1e30f, xl = 0.0f;
    #pragma unroll
    for (int c = 0; c < C_; ++c) {
        x[c] = pc[(size_t)c * A_];
        m = fmaxf(m, x[c]);
        xl = (c == lab) ? x[c] : xl;
    }
    float s = 0.0f;
    #pragma unroll
    for (int c = 0; c < C_; ++c) s += __expf(x[c] - m);
    const float ce = m + __logf(s) - xl;

    if (valid) loss_neg[(size_t)b * A_ + a_r] = pos ? 0.0f : ce;

    float sl1 = 0.0f, cep = 0.0f; int pcnt = 0;
    if (pos) {
        const float gl = sg[bi][0], gt = sg[bi][1], gr = sg[bi][2], gb = sg[bi][3];
        const float gcx = (gl + gr) * 0.5f, gcy = (gt + gb) * 0.5f;
        const float gw = gr - gl, gh = gb - gt;
        float t[4];
        t[0] = (gcx - acx) / (aw * 0.1f);
        t[1] = (gcy - acy) / (ah * 0.1f);
        t[2] = __logf(fmaxf(gw, 1e-6f) / aw) * 5.0f;   // /0.2
        t[3] = __logf(fmaxf(gh, 1e-6f) / ah) * 5.0f;
        const float* pr = preg + (size_t)b * 4 * A_ + a;
        #pragma unroll
        for (int k = 0; k < 4; ++k) {
            const float d  = pr[(size_t)k * A_] - t[k];
            const float ad = fabsf(d);
            sl1 += (ad < 1.0f) ? 0.5f * d * d : ad - 0.5f;
        }
        cep = ce; pcnt = 1;
    }

    // block reduce: wave shuffle then cross-wave via LDS; 3 atomics per block
    for (int o = 32; o > 0; o >>= 1) {
        sl1  += __shfl_down(sl1, o);
        cep  += __shfl_down(cep, o);
        pcnt += __shfl_down(pcnt, o);
    }
    if (lane == 0) { redf[wid] = sl1; redf[4 + wid] = cep; redi[wid] = pcnt; }
    __syncthreads();
    if (tid == 0) {
        const int   c_ = redi[0] + redi[1] + redi[2] + redi[3];
        if (c_ > 0) {
            const float s1 = redf[0] + redf[1] + redf[2] + redf[3];
            const float s2 = redf[4] + redf[5] + redf[6] + redf[7];
            atomicAdd(&pos_cnt[b], c_);
            atomicAdd(&ce_pos_sum[b], s2);
            atomicAdd(&sl1_b[b], s1);
        }
    }
}

// ---------------- Kernel 2: per-image OHEM top-K sum ----------------
// 1024 threads (16 waves) + 4-pass 8-bit radix select (exact K-th largest).
__global__ __launch_bounds__(1024) void k_ohem(
    const float* __restrict__ loss_neg,
    const int*   __restrict__ pos_cnt,
    const float* __restrict__ ce_pos_sum,
    float* __restrict__ acc_conf)
{
    __shared__ unsigned sv[A_];     // ~35 KB
    __shared__ int hA[256], hB[256];
    __shared__ int state[2];        // [0]=prefix bits, [1]=need
    __shared__ float fred[16];
    __shared__ int   ired[16];
    const int b    = blockIdx.x;
    const int tid  = threadIdx.x;
    const int wid  = tid >> 6;
    const int lane = tid & 63;
    const int np   = pos_cnt[b];

    for (int i = tid; i < A_; i += 1024)
        sv[i] = __float_as_uint(loss_neg[(size_t)b * A_ + i]);
    __syncthreads();

    if (np == 0) {
        // nums_pos clipped to EPS16; rank < 3*EPS16 selects only rank 0.
        unsigned mx = 0u;
        for (int i = tid; i < A_; i += 1024) mx = max(mx, sv[i]);
        for (int o = 32; o > 0; o >>= 1)
            mx = max(mx, (unsigned)__shfl_down((int)mx, o));
        if (lane == 0) ired[wid] = (int)mx;
        __syncthreads();
        if (tid == 0) {
            unsigned m2 = 0u;
            for (int w = 0; w < 16; ++w) m2 = max(m2, (unsigned)ired[w]);
            atomicAdd(acc_conf, __uint_as_float(m2) * 1024.0f * (1.0f / (float)B_));
        }
        return;
    }

    const int K = min(3 * np, A_);

    // 4-pass radix select: after pass p the top (4-p) bytes of the K-th
    // largest value are fixed in `prefix`.
    unsigned prefix = 0u; int need = K;
    #pragma unroll
    for (int p = 3; p >= 0; --p) {
        if (tid < 256) hA[tid] = 0;
        __syncthreads();
        const int sh = 8 * p;
        for (int i = tid; i < A_; i += 1024) {
            const unsigned u = sv[i];
            const bool mt = (p == 3) || ((u >> (sh + 8)) == prefix);
            if (mt) atomicAdd(&hA[(u >> sh) & 255], 1);
        }
        __syncthreads();
        // suffix-inclusive scan: S[t] = sum_{j>=t} h[j]  (Hillis-Steele, ping-pong)
        int* src = hA; int* dst = hB;
        for (int d = 1; d < 256; d <<= 1) {
            if (tid < 256) {
                int v = src[tid];
                if (tid + d < 256) v += src[tid + d];
                dst[tid] = v;
            }
            __syncthreads();
            int* tmp = src; src = dst; dst = tmp;
        }
        if (tid < 256) {
            const int St  = src[tid];
            const int St1 = (tid < 255) ? src[tid + 1] : 0;
            if (St >= need && St1 < need) {   // unique crossing
                state[0] = (int)((prefix << 8) | (unsigned)tid);
                state[1] = need - St1;
            }
        }
        __syncthreads();
        prefix = (unsigned)state[0]; need = state[1];
        __syncthreads();
    }
    const unsigned thr = prefix;   // exact K-th largest (uint order == float order, CE>=0)

    // sum strictly above threshold + tie fill-in (value-exact under ties)
    float ssum = 0.0f; int cgt = 0;
    for (int i = tid; i < A_; i += 1024) {
        const unsigned u = sv[i];
        if (u > thr) { ssum += __uint_as_float(u); ++cgt; }
    }
    for (int o = 32; o > 0; o >>= 1) {
        ssum += __shfl_down(ssum, o);
        cgt  += __shfl_down(cgt, o);
    }
    if (lane == 0) { fred[wid] = ssum; ired[wid] = cgt; }
    __syncthreads();
    if (tid == 0) {
        float sgt = 0.0f; int ngt = 0;
        for (int w = 0; w < 16; ++w) { sgt += fred[w]; ngt += ired[w]; }
        const float fnp = (float)np;
        const float l_neg = (sgt + (float)(K - ngt) * __uint_as_float(thr)) / fnp;
        const float l_pos = ce_pos_sum[b] / fnp;
        atomicAdd(acc_conf, (l_neg + l_pos) * (1.0f / (float)B_));
    }
}

// ---------------- Kernel 3: finalize (fp32 out) ----------------
__global__ void k_final(const float* __restrict__ sl1_b,
                        const int*   __restrict__ pos_cnt,
                        const float* __restrict__ acc_conf,
                        float* __restrict__ out)
{
    if (threadIdx.x == 0 && blockIdx.x == 0) {
        int tot = 0; float s1 = 0.0f;
        for (int b = 0; b < B_; ++b) { tot += pos_cnt[b]; s1 += sl1_b[b]; }
        const float np_total = fmaxf((float)tot, 1.0f);
        out[0] = s1 / np_total + acc_conf[0];
    }
}

extern "C" void kernel_launch(void* const* d_in, const int* in_sizes, int n_in,
                              void* d_out, int out_size, void* d_ws, size_t ws_size,
                              hipStream_t stream)
{
    const float* preg = (const float*)d_in[0];
    const float* pcls = (const float*)d_in[1];
    const float* ancs = (const float*)d_in[2];
    const float* gbox = (const float*)d_in[3];
    const int*   glab = (const int*)d_in[4];
    float* out = (float*)d_out;

    // workspace layout
    float* loss_neg   = (float*)d_ws;                        // B*A floats
    int*   pos_cnt    = (int*)(loss_neg + (size_t)B_ * A_);  // B ints
    float* ce_pos_sum = (float*)(pos_cnt + B_);              // B floats
    float* sl1_b      = ce_pos_sum + B_;                     // B floats
    float* acc_conf   = sl1_b + B_;                          // 1 float

    // zero accumulators (ws is poisoned 0xAA before every call)
    hipMemsetAsync(pos_cnt, 0, (size_t)(3 * B_ + 1) * sizeof(float), stream);

    dim3 g1((A_ + 255) / 256, B_);
    k_match_ce<<<g1, 256, 0, stream>>>(preg, pcls, ancs, gbox, glab,
                                       loss_neg, pos_cnt, ce_pos_sum, sl1_b);
    k_ohem<<<B_, 1024, 0, stream>>>(loss_neg, pos_cnt, ce_pos_sum, acc_conf);
    k_final<<<1, 64, 0, stream>>>(sl1_b, pos_cnt, acc_conf, out);
}